// Round 8
// baseline (320.605 us; speedup 1.0000x reference)
//
#include <hip/hip_runtime.h>
#include <math.h>

#define Bq 16
#define Sq 1024
#define Dq 128
#define Hq 8
#define DHq 16
#define DFFq 512
#define Lq 3
#define NCLS 6
#define NROWS (Bq * Sq)       // 16384
#define NX ((size_t)NROWS * Dq)   // 2,097,152 floats

typedef __attribute__((ext_vector_type(8))) short    bf16x8;
typedef __attribute__((ext_vector_type(4))) float    f32x4;
typedef __attribute__((ext_vector_type(4))) _Float16 f16x4;
typedef __attribute__((ext_vector_type(8))) _Float16 f16x8;

__device__ inline ushort f32_to_bf16(float f) {
    union { float f; unsigned u; } v; v.f = f;
    unsigned r = v.u + 0x7fffu + ((v.u >> 16) & 1u);
    return (ushort)(r >> 16);
}

// ---------------------------------------------------------------------------
// prep: cast+transpose weights to bf16 Wt[n][k]; cast x to bf16.
// Wq PRE-SCALED by 0.25 (ReLU commutes with positive scale).
// ---------------------------------------------------------------------------
__global__ __launch_bounds__(256) void prep_kernel(
    const float* __restrict__ Wqp, const float* __restrict__ Wkp,
    const float* __restrict__ Wvp, const float* __restrict__ W1p,
    const float* __restrict__ W2p, const float* __restrict__ xp,
    ushort* __restrict__ wbf, ushort* __restrict__ xbf)
{
    const int gid = blockIdx.x * 256 + threadIdx.x;
    if (gid < 147456) {                       // QKV transpose
        const int w   = gid / 49152;
        const int rem = gid - w * 49152;
        const int l   = rem >> 14;
        const int idx = rem & 16383;
        const int k   = idx >> 7;
        const int n   = idx & 127;
        const float* src = (w == 0) ? Wqp : (w == 1) ? Wkp : Wvp;
        const float scl = (w == 0) ? 0.25f : 1.0f;
        wbf[(size_t)(w * 3 + l) * 16384 + n * 128 + k] =
            f32_to_bf16(src[(size_t)l * 16384 + k * 128 + n] * scl);
    } else if (gid < 344064) {                // W1 [128][512]->[512][128]
        const int g   = gid - 147456;
        const int l   = g >> 16;
        const int idx = g & 65535;
        const int k   = idx >> 9;
        const int n   = idx & 511;
        wbf[147456 + (size_t)l * 65536 + n * 128 + k] =
            f32_to_bf16(W1p[(size_t)l * 65536 + k * 512 + n]);
    } else if (gid < 540672) {                // W2 [512][128]->[128][512]
        const int g   = gid - 344064;
        const int l   = g >> 16;
        const int idx = g & 65535;
        const int k   = idx >> 7;
        const int n   = idx & 127;
        wbf[344064 + (size_t)l * 65536 + n * 512 + k] =
            f32_to_bf16(W2p[(size_t)l * 65536 + k * 128 + n]);
    } else {                                  // x cast
        const int g = gid - 540672;
        xbf[g] = f32_to_bf16(xp[g]);
    }
}

// ---------------------------------------------------------------------------
// Fused QKV GEMM: grid (256, 3). y selects weight/bias/output layout.
// y=0: Q (pre-scaled) -> [b,h,s,dh] f16  y=1: K -> [b,h,s,dh] f16
// y=2: V -> vt [b,h,dh,s] f16
// ---------------------------------------------------------------------------
__global__ __launch_bounds__(256) void gemm_qkv(
    const ushort* __restrict__ A,
    const ushort* __restrict__ wq, const ushort* __restrict__ wk,
    const ushort* __restrict__ wv,
    const float* __restrict__ bqp, const float* __restrict__ bkp,
    const float* __restrict__ bvp,
    _Float16* __restrict__ qo, _Float16* __restrict__ ko,
    _Float16* __restrict__ vo)
{
    __shared__ ushort As[64 * 40];
    __shared__ ushort Bs[128 * 40];

    const int sel  = blockIdx.y;
    const ushort* Bt   = (sel == 0) ? wq : (sel == 1) ? wk : wv;
    const float*  bias = (sel == 0) ? bqp : (sel == 1) ? bkp : bvp;
    const float   bscl = (sel == 0) ? 0.25f : 1.0f;

    const int tid  = threadIdx.x;
    const int row0 = blockIdx.x * 64;
    const int wave = tid >> 6;
    const int lane = tid & 63;
    const int quad = lane >> 4;
    const int m16  = lane & 15;
    const int wm   = wave >> 1;
    const int wn   = wave & 1;

    const int sar = tid >> 2;
    const int sac = (tid & 3) * 8;

    f32x4 acc[2][4];
    #pragma unroll
    for (int i = 0; i < 2; ++i)
        #pragma unroll
        for (int j = 0; j < 4; ++j) acc[i][j] = (f32x4)0.f;

    for (int k0 = 0; k0 < 128; k0 += 32) {
        bf16x8 av = *(const bf16x8*)(A + (size_t)(row0 + sar) * 128 + k0 + sac);
        const int r1 = tid >> 2, r2 = r1 + 64;
        bf16x8 bv1 = *(const bf16x8*)(Bt + (size_t)r1 * 128 + k0 + sac);
        bf16x8 bv2 = *(const bf16x8*)(Bt + (size_t)r2 * 128 + k0 + sac);

        __syncthreads();
        *(bf16x8*)&As[sar * 40 + sac] = av;
        *(bf16x8*)&Bs[r1 * 40 + sac]  = bv1;
        *(bf16x8*)&Bs[r2 * 40 + sac]  = bv2;
        __syncthreads();

        bf16x8 af[2], bf[4];
        #pragma unroll
        for (int i = 0; i < 2; ++i)
            af[i] = *(const bf16x8*)&As[(32 * wm + 16 * i + m16) * 40 + quad * 8];
        #pragma unroll
        for (int j = 0; j < 4; ++j)
            bf[j] = *(const bf16x8*)&Bs[(64 * wn + 16 * j + m16) * 40 + quad * 8];
        #pragma unroll
        for (int i = 0; i < 2; ++i)
            #pragma unroll
            for (int j = 0; j < 4; ++j)
                acc[i][j] = __builtin_amdgcn_mfma_f32_16x16x32_bf16(af[i], bf[j], acc[i][j], 0, 0, 0);
    }

    #pragma unroll
    for (int i = 0; i < 2; ++i) {
        #pragma unroll
        for (int j = 0; j < 4; ++j) {
            const int col = 64 * wn + 16 * j + m16;
            const float bb = bias[col] * bscl;
            const int hh = col >> 4, dh = col & 15;
            #pragma unroll
            for (int r = 0; r < 4; ++r) {
                float val = fmaxf(acc[i][j][r] + bb, 0.f);
                const int gr = row0 + 32 * wm + 16 * i + quad * 4 + r;
                const int b = gr >> 10, s = gr & 1023;
                if (sel == 2) {
                    vo[(((size_t)b * Hq + hh) * DHq + dh) * Sq + s] = (_Float16)val;
                } else {
                    _Float16* outp = (sel == 0) ? qo : ko;
                    outp[(((size_t)b * Hq + hh) * Sq + s) * DHq + dh] = (_Float16)val;
                }
            }
        }
    }
}

// ---------------------------------------------------------------------------
// Fused LN1 + FFN1: grid (256, 4), tile 64 x 128 of [16384 x 512].
// Prologue: per-row (o + resid) LayerNorm via wave shuffles (16 rows/wave),
// normalized bf16 A-tile written to RESIDENT LDS (reused across all K-chunks).
// y==0 blocks also write xa fp32 (residual for FFN2). Then MFMA K-loop
// (K=128) staging only B; epilogue relu -> h_bf.
// ---------------------------------------------------------------------------
__global__ __launch_bounds__(256) void gemm_ffn1_ln(
    const float* __restrict__ o, const float* __restrict__ resid,
    const float* __restrict__ g, const float* __restrict__ beta,
    const ushort* __restrict__ Bt, const float* __restrict__ bias,
    float* __restrict__ xa, ushort* __restrict__ h_bf)
{
    __shared__ ushort Af[64 * 136];   // resident normalized A-tile (pad 8)
    __shared__ ushort Bs[128 * 40];

    const int tid  = threadIdx.x;
    const int row0 = blockIdx.x * 64;
    const int col0 = blockIdx.y * 128;
    const int wave = tid >> 6;
    const int lane = tid & 63;
    const int quad = lane >> 4;
    const int m16  = lane & 15;
    const int wm   = wave >> 1;
    const int wn   = wave & 1;

    // ---- prologue: LN of 16 rows per wave ----
    for (int it = 0; it < 16; ++it) {
        const int rr = wave * 16 + it;
        const size_t base = (size_t)(row0 + rr) * Dq;
        float v0 = o[base + lane]      + resid[base + lane];
        float v1 = o[base + 64 + lane] + resid[base + 64 + lane];

        float s = v0 + v1;
        #pragma unroll
        for (int off = 32; off > 0; off >>= 1) s += __shfl_xor(s, off, 64);
        const float mu = s * (1.f / 128.f);
        const float d0 = v0 - mu, d1 = v1 - mu;
        float vs = d0 * d0 + d1 * d1;
        #pragma unroll
        for (int off = 32; off > 0; off >>= 1) vs += __shfl_xor(vs, off, 64);
        const float rstd = rsqrtf(vs * (1.f / 128.f) + 1e-8f);

        const float r0 = g[lane]      * d0 * rstd + beta[lane];
        const float r1 = g[lane + 64] * d1 * rstd + beta[lane + 64];
        Af[rr * 136 + lane]      = f32_to_bf16(r0);
        Af[rr * 136 + 64 + lane] = f32_to_bf16(r1);
        if (blockIdx.y == 0) {
            xa[base + lane]      = r0;
            xa[base + 64 + lane] = r1;
        }
    }
    __syncthreads();

    const int sac = (tid & 3) * 8;

    f32x4 acc[2][4];
    #pragma unroll
    for (int i = 0; i < 2; ++i)
        #pragma unroll
        for (int j = 0; j < 4; ++j) acc[i][j] = (f32x4)0.f;

    for (int k0 = 0; k0 < 128; k0 += 32) {
        const int r1 = tid >> 2, r2 = r1 + 64;
        bf16x8 bv1 = *(const bf16x8*)(Bt + (size_t)(col0 + r1) * 128 + k0 + sac);
        bf16x8 bv2 = *(const bf16x8*)(Bt + (size_t)(col0 + r2) * 128 + k0 + sac);

        __syncthreads();
        *(bf16x8*)&Bs[r1 * 40 + sac] = bv1;
        *(bf16x8*)&Bs[r2 * 40 + sac] = bv2;
        __syncthreads();

        bf16x8 af[2], bf[4];
        #pragma unroll
        for (int i = 0; i < 2; ++i)
            af[i] = *(const bf16x8*)&Af[(32 * wm + 16 * i + m16) * 136 + k0 + quad * 8];
        #pragma unroll
        for (int j = 0; j < 4; ++j)
            bf[j] = *(const bf16x8*)&Bs[(64 * wn + 16 * j + m16) * 40 + quad * 8];
        #pragma unroll
        for (int i = 0; i < 2; ++i)
            #pragma unroll
            for (int j = 0; j < 4; ++j)
                acc[i][j] = __builtin_amdgcn_mfma_f32_16x16x32_bf16(af[i], bf[j], acc[i][j], 0, 0, 0);
    }

    #pragma unroll
    for (int i = 0; i < 2; ++i) {
        #pragma unroll
        for (int j = 0; j < 4; ++j) {
            const int col = col0 + 64 * wn + 16 * j + m16;
            const float bb = bias[col];
            #pragma unroll
            for (int r = 0; r < 4; ++r) {
                float val = fmaxf(acc[i][j][r] + bb, 0.f);
                const int gr = row0 + 32 * wm + 16 * i + quad * 4 + r;
                h_bf[(size_t)gr * DFFq + col] = f32_to_bf16(val);
            }
        }
    }
}

// ---------------------------------------------------------------------------
// Fused FFN2 + residual + LayerNorm2 (+ final projection on last layer).
// Block tile 64 rows x 128 cols = FULL rows -> LN completes in-block.
// last==0: write xb fp32 + xbbf bf16.  last==1: normalized rows -> LDS,
// then out[64x6] = rows @ Wout + bout (Wout staged in LDS).
// ---------------------------------------------------------------------------
__global__ __launch_bounds__(256) void gemm_ffn2_ln(
    const ushort* __restrict__ A, const ushort* __restrict__ Bt,
    const float* __restrict__ bias, const float* __restrict__ resid,
    const float* __restrict__ g, const float* __restrict__ beta,
    float* __restrict__ xb, ushort* __restrict__ xbbf,
    const float* __restrict__ Wout, const float* __restrict__ bout,
    float* __restrict__ out, int last)
{
    __shared__ __align__(16) char smem_raw[36608];
    ushort* As   = (ushort*)smem_raw;            // [0, 5120) B
    ushort* Bs   = (ushort*)smem_raw + 2560;     // [5120, 15360) B
    float*  vals = (float*)smem_raw;             // [0, 33024) B  (post-K-loop)
    float*  mus  = (float*)smem_raw + 8256;      // [33024, 33280)
    float*  rsds = (float*)smem_raw + 8320;      // [33280, 33536)
    float*  wo_s = (float*)smem_raw + 8384;      // [33536, 36608) : Wout 768 f32

    const int tid  = threadIdx.x;
    const int row0 = blockIdx.x * 64;
    const int wave = tid >> 6;
    const int lane = tid & 63;
    const int quad = lane >> 4;
    const int m16  = lane & 15;
    const int wm   = wave >> 1;
    const int wn   = wave & 1;

    if (last) {
        #pragma unroll
        for (int i = 0; i < 3; ++i) wo_s[tid + i * 256] = Wout[tid + i * 256];
    }

    const int sar = tid >> 2;
    const int sac = (tid & 3) * 8;

    f32x4 acc[2][4];
    #pragma unroll
    for (int i = 0; i < 2; ++i)
        #pragma unroll
        for (int j = 0; j < 4; ++j) acc[i][j] = (f32x4)0.f;

    for (int k0 = 0; k0 < DFFq; k0 += 32) {
        bf16x8 av = *(const bf16x8*)(A + (size_t)(row0 + sar) * DFFq + k0 + sac);
        const int r1 = tid >> 2, r2 = r1 + 64;
        bf16x8 bv1 = *(const bf16x8*)(Bt + (size_t)r1 * DFFq + k0 + sac);
        bf16x8 bv2 = *(const bf16x8*)(Bt + (size_t)r2 * DFFq + k0 + sac);

        __syncthreads();
        *(bf16x8*)&As[sar * 40 + sac] = av;
        *(bf16x8*)&Bs[r1 * 40 + sac]  = bv1;
        *(bf16x8*)&Bs[r2 * 40 + sac]  = bv2;
        __syncthreads();

        bf16x8 af[2], bf[4];
        #pragma unroll
        for (int i = 0; i < 2; ++i)
            af[i] = *(const bf16x8*)&As[(32 * wm + 16 * i + m16) * 40 + quad * 8];
        #pragma unroll
        for (int j = 0; j < 4; ++j)
            bf[j] = *(const bf16x8*)&Bs[(64 * wn + 16 * j + m16) * 40 + quad * 8];
        #pragma unroll
        for (int i = 0; i < 2; ++i)
            #pragma unroll
            for (int j = 0; j < 4; ++j)
                acc[i][j] = __builtin_amdgcn_mfma_f32_16x16x32_bf16(af[i], bf[j], acc[i][j], 0, 0, 0);
    }

    __syncthreads();   // staging dead; vals takes over

    float vreg[2][4][4];
    #pragma unroll
    for (int i = 0; i < 2; ++i) {
        #pragma unroll
        for (int j = 0; j < 4; ++j) {
            const int col = 64 * wn + 16 * j + m16;
            const float bb = bias[col];
            #pragma unroll
            for (int r = 0; r < 4; ++r) {
                const int grow = 32 * wm + 16 * i + quad * 4 + r;
                float v = acc[i][j][r] + bb + resid[(size_t)(row0 + grow) * Dq + col];
                vreg[i][j][r] = v;
                vals[grow * 129 + col] = v;
            }
        }
    }
    __syncthreads();

    if (tid < 64) {
        float s = 0.f, s2 = 0.f;
        #pragma unroll 8
        for (int c = 0; c < Dq; ++c) {
            float x = vals[tid * 129 + c];
            s += x; s2 = fmaf(x, x, s2);
        }
        const float mu  = s * (1.f / 128.f);
        const float var = s2 * (1.f / 128.f) - mu * mu;
        mus[tid]  = mu;
        rsds[tid] = rsqrtf(var + 1e-6f);
    }
    __syncthreads();

    if (!last) {
        #pragma unroll
        for (int i = 0; i < 2; ++i) {
            #pragma unroll
            for (int r = 0; r < 4; ++r) {
                const int grow = 32 * wm + 16 * i + quad * 4 + r;
                const float mu = mus[grow];
                const float rs = rsds[grow];
                #pragma unroll
                for (int j = 0; j < 4; ++j) {
                    const int col = 64 * wn + 16 * j + m16;
                    const float rn = g[col] * (vreg[i][j][r] - mu) * rs + beta[col];
                    const size_t idx = (size_t)(row0 + grow) * Dq + col;
                    xb[idx]   = rn;
                    xbbf[idx] = f32_to_bf16(rn);
                }
            }
        }
    } else {
        // normalized rows back to LDS, then 64x6 projection
        #pragma unroll
        for (int i = 0; i < 2; ++i) {
            #pragma unroll
            for (int r = 0; r < 4; ++r) {
                const int grow = 32 * wm + 16 * i + quad * 4 + r;
                const float mu = mus[grow];
                const float rs = rsds[grow];
                #pragma unroll
                for (int j = 0; j < 4; ++j) {
                    const int col = 64 * wn + 16 * j + m16;
                    vals[grow * 129 + col] = g[col] * (vreg[i][j][r] - mu) * rs + beta[col];
                }
            }
        }
        __syncthreads();
        for (int idx = tid; idx < 64 * NCLS; idx += 256) {
            const int row = idx / NCLS;
            const int c   = idx - row * NCLS;
            float a = bout[c];
            #pragma unroll 8
            for (int kk = 0; kk < Dq; ++kk)
                a = fmaf(vals[row * 129 + kk], wo_s[kk * NCLS + c], a);
            out[(size_t)(row0 + row) * NCLS + c] = a;
        }
    }
}

// ---------------------------------------------------------------------------
// f16 MFMA flash attention, LDS-staged (R6 structure, R7 pre-scaled Q).
// ---------------------------------------------------------------------------
__global__ __launch_bounds__(256) void attn_mfma(
    const _Float16* __restrict__ q, const _Float16* __restrict__ k,
    const _Float16* __restrict__ vt, float* __restrict__ o)
{
    __shared__ _Float16 Ks[256 * 20];
    __shared__ _Float16 Vs[16 * 264];

    const int bh   = blockIdx.x;
    const int qc   = blockIdx.y;
    const int b    = bh >> 3;
    const int h    = bh & 7;
    const int tid  = threadIdx.x;
    const int wave = tid >> 6;
    const int lane = tid & 63;
    const int quad = lane >> 4;
    const int m16  = lane & 15;
    const int q0   = qc * 128 + wave * 32;

    const f16x4 qf0 = *(const f16x4*)(q + (((size_t)bh * Sq) + q0 + m16) * DHq + quad * 4);
    const f16x4 qf1 = *(const f16x4*)(q + (((size_t)bh * Sq) + q0 + 16 + m16) * DHq + quad * 4);

    const _Float16* kg  = k  + (size_t)bh * Sq * DHq;
    const _Float16* vtg = vt + (size_t)bh * DHq * Sq;

    f32x4 oacc0 = (f32x4)0.f, oacc1 = (f32x4)0.f;
    float lacc0 = 0.f, lacc1 = 0.f;

    const int krow = tid;
    const int vrow = tid >> 4;
    const int vcol = (tid & 15) * 16;

    for (int kb = 0; kb < 4; ++kb) {
        f16x8 ka  = *(const f16x8*)(kg + ((size_t)kb * 256 + krow) * DHq);
        f16x8 kb8 = *(const f16x8*)(kg + ((size_t)kb * 256 + krow) * DHq + 8);
        f16x8 va  = *(const f16x8*)(vtg + (size_t)vrow * Sq + kb * 256 + vcol);
        f16x8 vb  = *(const f16x8*)(vtg + (size_t)vrow * Sq + kb * 256 + vcol + 8);
        __syncthreads();
        *(f16x8*)&Ks[krow * 20 + 0] = ka;
        *(f16x8*)&Ks[krow * 20 + 8] = kb8;
        *(f16x8*)&Vs[vrow * 264 + vcol + 0] = va;
        *(f16x8*)&Vs[vrow * 264 + vcol + 8] = vb;
        __syncthreads();

        #pragma unroll 4
        for (int kt = 0; kt < 16; ++kt) {
            const f16x4 kf = *(const f16x4*)&Ks[(kt * 16 + m16) * 20 + quad * 4];
            const f16x4 vf = *(const f16x4*)&Vs[m16 * 264 + kt * 16 + quad * 4];

            f32x4 st0 = __builtin_amdgcn_mfma_f32_16x16x16f16(kf, qf0, (f32x4)0.f, 0, 0, 0);
            f32x4 st1 = __builtin_amdgcn_mfma_f32_16x16x16f16(kf, qf1, (f32x4)0.f, 0, 0, 0);

            float p00 = __expf(st0[0]);
            float p01 = __expf(st0[1]);
            float p02 = __expf(st0[2]);
            float p03 = __expf(st0[3]);
            float p10 = __expf(st1[0]);
            float p11 = __expf(st1[1]);
            float p12 = __expf(st1[2]);
            float p13 = __expf(st1[3]);
            lacc0 += (p00 + p01) + (p02 + p03);
            lacc1 += (p10 + p11) + (p12 + p13);

            f16x4 pf0, pf1;
            pf0[0] = (_Float16)p00; pf0[1] = (_Float16)p01;
            pf0[2] = (_Float16)p02; pf0[3] = (_Float16)p03;
            pf1[0] = (_Float16)p10; pf1[1] = (_Float16)p11;
            pf1[2] = (_Float16)p12; pf1[3] = (_Float16)p13;

            oacc0 = __builtin_amdgcn_mfma_f32_16x16x16f16(pf0, vf, oacc0, 0, 0, 0);
            oacc1 = __builtin_amdgcn_mfma_f32_16x16x16f16(pf1, vf, oacc1, 0, 0, 0);
        }
    }

    lacc0 += __shfl_xor(lacc0, 16, 64);
    lacc0 += __shfl_xor(lacc0, 32, 64);
    lacc1 += __shfl_xor(lacc1, 16, 64);
    lacc1 += __shfl_xor(lacc1, 32, 64);

    #pragma unroll
    for (int r = 0; r < 4; ++r) {
        const float ls0 = __shfl(lacc0, quad * 4 + r, 64);
        const float ls1 = __shfl(lacc1, quad * 4 + r, 64);
        o[((size_t)b * Sq + q0 + quad * 4 + r) * Dq + h * DHq + m16]      = oacc0[r] / ls0;
        o[((size_t)b * Sq + q0 + 16 + quad * 4 + r) * Dq + h * DHq + m16] = oacc1[r] / ls1;
    }
}

// ---------------------------------------------------------------------------
extern "C" void kernel_launch(void* const* d_in, const int* in_sizes, int n_in,
                              void* d_out, int out_size, void* d_ws, size_t ws_size,
                              hipStream_t stream)
{
    const float* x_in  = (const float*)d_in[0];
    const float* Wq    = (const float*)d_in[1];
    const float* bq    = (const float*)d_in[2];
    const float* Wk    = (const float*)d_in[3];
    const float* bk    = (const float*)d_in[4];
    const float* Wv    = (const float*)d_in[5];
    const float* bv    = (const float*)d_in[6];
    const float* ln1_g = (const float*)d_in[7];
    const float* ln1_b = (const float*)d_in[8];
    const float* W1    = (const float*)d_in[9];
    const float* b1    = (const float*)d_in[10];
    const float* W2    = (const float*)d_in[11];
    const float* b2    = (const float*)d_in[12];
    const float* ln2_g = (const float*)d_in[13];
    const float* ln2_b = (const float*)d_in[14];
    const float* Wout  = (const float*)d_in[15];
    const float* bout  = (const float*)d_in[16];
    float* out = (float*)d_out;

    // Workspace (float units). h_bf spans [0, 2NX) and aliases q16/k16/vt16
    // (dead after attention). obuf moved to 8NX so ffn1_ln can read it while
    // writing h_bf. Total 9NX = 75.5 MB.
    float* ws = (float*)d_ws;
    _Float16* qf16 = (_Float16*)ws;                         // [0, 0.5NX)
    _Float16* kf16 = (_Float16*)(ws + NX / 2);              // [0.5, 1NX)
    _Float16* vt16 = (_Float16*)(ws + NX);                  // [1, 1.5NX)
    ushort*   h_bf = (ushort*)ws;                           // [0, 2NX)
    float*    xa   = ws + 7 * NX / 2;                       // [3.5, 4.5NX)
    float*    xb   = ws + 9 * NX / 2;                       // [4.5, 5.5NX)
    ushort*   xbf0 = (ushort*)(ws + 11 * NX / 2);           // [5.5, 6NX)
    ushort*   xbbf = (ushort*)(ws + 13 * NX / 2);           // [6.5, 7NX)
    ushort*   wbf  = (ushort*)(ws + 7 * NX);                // [7, ~7.26NX)
    float*    obuf = ws + 8 * NX;                           // [8, 9NX)

    prep_kernel<<<dim3(10304), dim3(256), 0, stream>>>(Wq, Wk, Wv, W1, W2, x_in, wbf, xbf0);

    const dim3 blk(256);
    const float* xcur = x_in;
    const ushort* xcur_bf = xbf0;

    for (int l = 0; l < Lq; ++l) {
        const ushort* wqt = wbf + (size_t)(0 * 3 + l) * 16384;
        const ushort* wkt = wbf + (size_t)(1 * 3 + l) * 16384;
        const ushort* wvt = wbf + (size_t)(2 * 3 + l) * 16384;
        const ushort* w1t = wbf + 147456 + (size_t)l * 65536;
        const ushort* w2t = wbf + 344064 + (size_t)l * 65536;

        gemm_qkv<<<dim3(256, 3), blk, 0, stream>>>(
            xcur_bf, wqt, wkt, wvt, bq + l * Dq, bk + l * Dq, bv + l * Dq,
            qf16, kf16, vt16);

        attn_mfma<<<dim3(Bq * Hq, 8), blk, 0, stream>>>(qf16, kf16, vt16, obuf);

        gemm_ffn1_ln<<<dim3(256, 4), blk, 0, stream>>>(
            obuf, xcur, ln1_g + l * Dq, ln1_b + l * Dq, w1t, b1 + l * DFFq,
            xa, h_bf);

        gemm_ffn2_ln<<<dim3(256), blk, 0, stream>>>(
            h_bf, w2t, b2 + l * Dq, xa, ln2_g + l * Dq, ln2_b + l * Dq,
            xb, xbbf, Wout, bout, out, (l == Lq - 1) ? 1 : 0);

        xcur = xb;
        xcur_bf = xbbf;
    }
}

// Round 9
// 305.315 us; speedup vs baseline: 1.0501x; 1.0501x over previous
//
#include <hip/hip_runtime.h>
#include <math.h>

#define Bq 16
#define Sq 1024
#define Dq 128
#define Hq 8
#define DHq 16
#define DFFq 512
#define Lq 3
#define NCLS 6
#define NROWS (Bq * Sq)       // 16384
#define NX ((size_t)NROWS * Dq)   // 2,097,152 floats

typedef __attribute__((ext_vector_type(8))) short    bf16x8;
typedef __attribute__((ext_vector_type(4))) float    f32x4;
typedef __attribute__((ext_vector_type(4))) _Float16 f16x4;
typedef __attribute__((ext_vector_type(8))) _Float16 f16x8;

__device__ inline ushort f32_to_bf16(float f) {
    union { float f; unsigned u; } v; v.f = f;
    unsigned r = v.u + 0x7fffu + ((v.u >> 16) & 1u);
    return (ushort)(r >> 16);
}

// ---------------------------------------------------------------------------
// prep: cast+transpose weights to bf16 Wt[n][k]; cast x to bf16.
// Wq PRE-SCALED by 0.25 (ReLU commutes with positive scale).
// ---------------------------------------------------------------------------
__global__ __launch_bounds__(256) void prep_kernel(
    const float* __restrict__ Wqp, const float* __restrict__ Wkp,
    const float* __restrict__ Wvp, const float* __restrict__ W1p,
    const float* __restrict__ W2p, const float* __restrict__ xp,
    ushort* __restrict__ wbf, ushort* __restrict__ xbf)
{
    const int gid = blockIdx.x * 256 + threadIdx.x;
    if (gid < 147456) {                       // QKV transpose
        const int w   = gid / 49152;
        const int rem = gid - w * 49152;
        const int l   = rem >> 14;
        const int idx = rem & 16383;
        const int k   = idx >> 7;
        const int n   = idx & 127;
        const float* src = (w == 0) ? Wqp : (w == 1) ? Wkp : Wvp;
        const float scl = (w == 0) ? 0.25f : 1.0f;
        wbf[(size_t)(w * 3 + l) * 16384 + n * 128 + k] =
            f32_to_bf16(src[(size_t)l * 16384 + k * 128 + n] * scl);
    } else if (gid < 344064) {                // W1 [128][512]->[512][128]
        const int g   = gid - 147456;
        const int l   = g >> 16;
        const int idx = g & 65535;
        const int k   = idx >> 9;
        const int n   = idx & 511;
        wbf[147456 + (size_t)l * 65536 + n * 128 + k] =
            f32_to_bf16(W1p[(size_t)l * 65536 + k * 512 + n]);
    } else if (gid < 540672) {                // W2 [512][128]->[128][512]
        const int g   = gid - 344064;
        const int l   = g >> 16;
        const int idx = g & 65535;
        const int k   = idx >> 7;
        const int n   = idx & 127;
        wbf[344064 + (size_t)l * 65536 + n * 512 + k] =
            f32_to_bf16(W2p[(size_t)l * 65536 + k * 128 + n]);
    } else {                                  // x cast
        const int g = gid - 540672;
        xbf[g] = f32_to_bf16(xp[g]);
    }
}

// ---------------------------------------------------------------------------
// Fused QKV GEMM: grid (256, 3). y selects weight/bias/output layout.
// y=0: Q (pre-scaled) -> [b,h,s,dh] f16  y=1: K -> [b,h,s,dh] f16
// y=2: V -> vt [b,h,dh,s] f16
// ---------------------------------------------------------------------------
__global__ __launch_bounds__(256) void gemm_qkv(
    const ushort* __restrict__ A,
    const ushort* __restrict__ wq, const ushort* __restrict__ wk,
    const ushort* __restrict__ wv,
    const float* __restrict__ bqp, const float* __restrict__ bkp,
    const float* __restrict__ bvp,
    _Float16* __restrict__ qo, _Float16* __restrict__ ko,
    _Float16* __restrict__ vo)
{
    __shared__ ushort As[64 * 40];
    __shared__ ushort Bs[128 * 40];

    const int sel  = blockIdx.y;
    const ushort* Bt   = (sel == 0) ? wq : (sel == 1) ? wk : wv;
    const float*  bias = (sel == 0) ? bqp : (sel == 1) ? bkp : bvp;
    const float   bscl = (sel == 0) ? 0.25f : 1.0f;

    const int tid  = threadIdx.x;
    const int row0 = blockIdx.x * 64;
    const int wave = tid >> 6;
    const int lane = tid & 63;
    const int quad = lane >> 4;
    const int m16  = lane & 15;
    const int wm   = wave >> 1;
    const int wn   = wave & 1;

    const int sar = tid >> 2;
    const int sac = (tid & 3) * 8;

    f32x4 acc[2][4];
    #pragma unroll
    for (int i = 0; i < 2; ++i)
        #pragma unroll
        for (int j = 0; j < 4; ++j) acc[i][j] = (f32x4)0.f;

    for (int k0 = 0; k0 < 128; k0 += 32) {
        bf16x8 av = *(const bf16x8*)(A + (size_t)(row0 + sar) * 128 + k0 + sac);
        const int r1 = tid >> 2, r2 = r1 + 64;
        bf16x8 bv1 = *(const bf16x8*)(Bt + (size_t)r1 * 128 + k0 + sac);
        bf16x8 bv2 = *(const bf16x8*)(Bt + (size_t)r2 * 128 + k0 + sac);

        __syncthreads();
        *(bf16x8*)&As[sar * 40 + sac] = av;
        *(bf16x8*)&Bs[r1 * 40 + sac]  = bv1;
        *(bf16x8*)&Bs[r2 * 40 + sac]  = bv2;
        __syncthreads();

        bf16x8 af[2], bf[4];
        #pragma unroll
        for (int i = 0; i < 2; ++i)
            af[i] = *(const bf16x8*)&As[(32 * wm + 16 * i + m16) * 40 + quad * 8];
        #pragma unroll
        for (int j = 0; j < 4; ++j)
            bf[j] = *(const bf16x8*)&Bs[(64 * wn + 16 * j + m16) * 40 + quad * 8];
        #pragma unroll
        for (int i = 0; i < 2; ++i)
            #pragma unroll
            for (int j = 0; j < 4; ++j)
                acc[i][j] = __builtin_amdgcn_mfma_f32_16x16x32_bf16(af[i], bf[j], acc[i][j], 0, 0, 0);
    }

    #pragma unroll
    for (int i = 0; i < 2; ++i) {
        #pragma unroll
        for (int j = 0; j < 4; ++j) {
            const int col = 64 * wn + 16 * j + m16;
            const float bb = bias[col] * bscl;
            const int hh = col >> 4, dh = col & 15;
            #pragma unroll
            for (int r = 0; r < 4; ++r) {
                float val = fmaxf(acc[i][j][r] + bb, 0.f);
                const int gr = row0 + 32 * wm + 16 * i + quad * 4 + r;
                const int b = gr >> 10, s = gr & 1023;
                if (sel == 2) {
                    vo[(((size_t)b * Hq + hh) * DHq + dh) * Sq + s] = (_Float16)val;
                } else {
                    _Float16* outp = (sel == 0) ? qo : ko;
                    outp[(((size_t)b * Hq + hh) * Sq + s) * DHq + dh] = (_Float16)val;
                }
            }
        }
    }
}

// ---------------------------------------------------------------------------
// Fused LN1 + FFN1 v2: grid (512). 32-row blocks; each row LN'd EXACTLY ONCE
// (8 rows/wave), normalized bf16 A-tile resident in LDS. Then loop the 4
// column chunks of DFF=512, staging B per 32-K-chunk. Every block writes its
// own 32 xa rows. Fixes R8's 4x-redundant-LN regression.
// ---------------------------------------------------------------------------
__global__ __launch_bounds__(256) void gemm_ffn1_ln(
    const float* __restrict__ o, const float* __restrict__ resid,
    const float* __restrict__ g, const float* __restrict__ beta,
    const ushort* __restrict__ Bt, const float* __restrict__ bias,
    float* __restrict__ xa, ushort* __restrict__ h_bf)
{
    __shared__ ushort Af[32 * 136];   // resident normalized A-tile (pad 8)
    __shared__ ushort Bs[128 * 40];

    const int tid  = threadIdx.x;
    const int row0 = blockIdx.x * 32;
    const int wave = tid >> 6;
    const int lane = tid & 63;
    const int quad = lane >> 4;
    const int m16  = lane & 15;
    const int wm   = wave >> 1;          // rows 16*wm
    const int wn   = wave & 1;           // cols 64*wn

    // ---- prologue: LN of 8 rows per wave (each row once, globally) ----
    #pragma unroll 2
    for (int it = 0; it < 8; ++it) {
        const int rr = wave * 8 + it;
        const size_t base = (size_t)(row0 + rr) * Dq;
        float v0 = o[base + lane]      + resid[base + lane];
        float v1 = o[base + 64 + lane] + resid[base + 64 + lane];

        float s = v0 + v1;
        #pragma unroll
        for (int off = 32; off > 0; off >>= 1) s += __shfl_xor(s, off, 64);
        const float mu = s * (1.f / 128.f);
        const float d0 = v0 - mu, d1 = v1 - mu;
        float vs = d0 * d0 + d1 * d1;
        #pragma unroll
        for (int off = 32; off > 0; off >>= 1) vs += __shfl_xor(vs, off, 64);
        const float rstd = rsqrtf(vs * (1.f / 128.f) + 1e-8f);

        const float r0 = g[lane]      * d0 * rstd + beta[lane];
        const float r1 = g[lane + 64] * d1 * rstd + beta[lane + 64];
        Af[rr * 136 + lane]      = f32_to_bf16(r0);
        Af[rr * 136 + 64 + lane] = f32_to_bf16(r1);
        xa[base + lane]      = r0;
        xa[base + 64 + lane] = r1;
    }

    const int sac = (tid & 3) * 8;
    const int r1  = tid >> 2, r2 = r1 + 64;

    for (int cc = 0; cc < 4; ++cc) {
        const int col0 = cc * 128;

        f32x4 acc[4];
        #pragma unroll
        for (int j = 0; j < 4; ++j) acc[j] = (f32x4)0.f;

        for (int k0 = 0; k0 < 128; k0 += 32) {
            bf16x8 bv1 = *(const bf16x8*)(Bt + (size_t)(col0 + r1) * 128 + k0 + sac);
            bf16x8 bv2 = *(const bf16x8*)(Bt + (size_t)(col0 + r2) * 128 + k0 + sac);

            __syncthreads();
            *(bf16x8*)&Bs[r1 * 40 + sac] = bv1;
            *(bf16x8*)&Bs[r2 * 40 + sac] = bv2;
            __syncthreads();

            const bf16x8 af = *(const bf16x8*)&Af[(16 * wm + m16) * 136 + k0 + quad * 8];
            bf16x8 bf[4];
            #pragma unroll
            for (int j = 0; j < 4; ++j)
                bf[j] = *(const bf16x8*)&Bs[(64 * wn + 16 * j + m16) * 40 + quad * 8];
            #pragma unroll
            for (int j = 0; j < 4; ++j)
                acc[j] = __builtin_amdgcn_mfma_f32_16x16x32_bf16(af, bf[j], acc[j], 0, 0, 0);
        }

        #pragma unroll
        for (int j = 0; j < 4; ++j) {
            const int col = col0 + 64 * wn + 16 * j + m16;
            const float bb = bias[col];
            #pragma unroll
            for (int r = 0; r < 4; ++r) {
                float val = fmaxf(acc[j][r] + bb, 0.f);
                const int gr = row0 + 16 * wm + quad * 4 + r;
                h_bf[(size_t)gr * DFFq + col] = f32_to_bf16(val);
            }
        }
    }
}

// ---------------------------------------------------------------------------
// Fused FFN2 + residual + LayerNorm2 (+ final projection on last layer).
// Block tile 64 rows x 128 cols = FULL rows -> LN completes in-block.
// last==0: write xb fp32 + xbbf bf16.  last==1: normalized rows -> LDS,
// then out[64x6] = rows @ Wout + bout (Wout staged in LDS).
// ---------------------------------------------------------------------------
__global__ __launch_bounds__(256) void gemm_ffn2_ln(
    const ushort* __restrict__ A, const ushort* __restrict__ Bt,
    const float* __restrict__ bias, const float* __restrict__ resid,
    const float* __restrict__ g, const float* __restrict__ beta,
    float* __restrict__ xb, ushort* __restrict__ xbbf,
    const float* __restrict__ Wout, const float* __restrict__ bout,
    float* __restrict__ out, int last)
{
    __shared__ __align__(16) char smem_raw[36608];
    ushort* As   = (ushort*)smem_raw;            // [0, 5120) B
    ushort* Bs   = (ushort*)smem_raw + 2560;     // [5120, 15360) B
    float*  vals = (float*)smem_raw;             // [0, 33024) B  (post-K-loop)
    float*  mus  = (float*)smem_raw + 8256;      // [33024, 33280)
    float*  rsds = (float*)smem_raw + 8320;      // [33280, 33536)
    float*  wo_s = (float*)smem_raw + 8384;      // [33536, 36608) : Wout 768 f32

    const int tid  = threadIdx.x;
    const int row0 = blockIdx.x * 64;
    const int wave = tid >> 6;
    const int lane = tid & 63;
    const int quad = lane >> 4;
    const int m16  = lane & 15;
    const int wm   = wave >> 1;
    const int wn   = wave & 1;

    if (last) {
        #pragma unroll
        for (int i = 0; i < 3; ++i) wo_s[tid + i * 256] = Wout[tid + i * 256];
    }

    const int sar = tid >> 2;
    const int sac = (tid & 3) * 8;

    f32x4 acc[2][4];
    #pragma unroll
    for (int i = 0; i < 2; ++i)
        #pragma unroll
        for (int j = 0; j < 4; ++j) acc[i][j] = (f32x4)0.f;

    for (int k0 = 0; k0 < DFFq; k0 += 32) {
        bf16x8 av = *(const bf16x8*)(A + (size_t)(row0 + sar) * DFFq + k0 + sac);
        const int r1 = tid >> 2, r2 = r1 + 64;
        bf16x8 bv1 = *(const bf16x8*)(Bt + (size_t)r1 * DFFq + k0 + sac);
        bf16x8 bv2 = *(const bf16x8*)(Bt + (size_t)r2 * DFFq + k0 + sac);

        __syncthreads();
        *(bf16x8*)&As[sar * 40 + sac] = av;
        *(bf16x8*)&Bs[r1 * 40 + sac]  = bv1;
        *(bf16x8*)&Bs[r2 * 40 + sac]  = bv2;
        __syncthreads();

        bf16x8 af[2], bf[4];
        #pragma unroll
        for (int i = 0; i < 2; ++i)
            af[i] = *(const bf16x8*)&As[(32 * wm + 16 * i + m16) * 40 + quad * 8];
        #pragma unroll
        for (int j = 0; j < 4; ++j)
            bf[j] = *(const bf16x8*)&Bs[(64 * wn + 16 * j + m16) * 40 + quad * 8];
        #pragma unroll
        for (int i = 0; i < 2; ++i)
            #pragma unroll
            for (int j = 0; j < 4; ++j)
                acc[i][j] = __builtin_amdgcn_mfma_f32_16x16x32_bf16(af[i], bf[j], acc[i][j], 0, 0, 0);
    }

    __syncthreads();   // staging dead; vals takes over

    float vreg[2][4][4];
    #pragma unroll
    for (int i = 0; i < 2; ++i) {
        #pragma unroll
        for (int j = 0; j < 4; ++j) {
            const int col = 64 * wn + 16 * j + m16;
            const float bb = bias[col];
            #pragma unroll
            for (int r = 0; r < 4; ++r) {
                const int grow = 32 * wm + 16 * i + quad * 4 + r;
                float v = acc[i][j][r] + bb + resid[(size_t)(row0 + grow) * Dq + col];
                vreg[i][j][r] = v;
                vals[grow * 129 + col] = v;
            }
        }
    }
    __syncthreads();

    if (tid < 64) {
        float s = 0.f, s2 = 0.f;
        #pragma unroll 8
        for (int c = 0; c < Dq; ++c) {
            float x = vals[tid * 129 + c];
            s += x; s2 = fmaf(x, x, s2);
        }
        const float mu  = s * (1.f / 128.f);
        const float var = s2 * (1.f / 128.f) - mu * mu;
        mus[tid]  = mu;
        rsds[tid] = rsqrtf(var + 1e-6f);
    }
    __syncthreads();

    if (!last) {
        #pragma unroll
        for (int i = 0; i < 2; ++i) {
            #pragma unroll
            for (int r = 0; r < 4; ++r) {
                const int grow = 32 * wm + 16 * i + quad * 4 + r;
                const float mu = mus[grow];
                const float rs = rsds[grow];
                #pragma unroll
                for (int j = 0; j < 4; ++j) {
                    const int col = 64 * wn + 16 * j + m16;
                    const float rn = g[col] * (vreg[i][j][r] - mu) * rs + beta[col];
                    const size_t idx = (size_t)(row0 + grow) * Dq + col;
                    xb[idx]   = rn;
                    xbbf[idx] = f32_to_bf16(rn);
                }
            }
        }
    } else {
        #pragma unroll
        for (int i = 0; i < 2; ++i) {
            #pragma unroll
            for (int r = 0; r < 4; ++r) {
                const int grow = 32 * wm + 16 * i + quad * 4 + r;
                const float mu = mus[grow];
                const float rs = rsds[grow];
                #pragma unroll
                for (int j = 0; j < 4; ++j) {
                    const int col = 64 * wn + 16 * j + m16;
                    vals[grow * 129 + col] = g[col] * (vreg[i][j][r] - mu) * rs + beta[col];
                }
            }
        }
        __syncthreads();
        for (int idx = tid; idx < 64 * NCLS; idx += 256) {
            const int row = idx / NCLS;
            const int c   = idx - row * NCLS;
            float a = bout[c];
            #pragma unroll 8
            for (int kk = 0; kk < Dq; ++kk)
                a = fmaf(vals[row * 129 + kk], wo_s[kk * NCLS + c], a);
            out[(size_t)(row0 + row) * NCLS + c] = a;
        }
    }
}

// ---------------------------------------------------------------------------
// f16 MFMA flash attention, LDS-staged (R6 structure, R7 pre-scaled Q).
// ---------------------------------------------------------------------------
__global__ __launch_bounds__(256) void attn_mfma(
    const _Float16* __restrict__ q, const _Float16* __restrict__ k,
    const _Float16* __restrict__ vt, float* __restrict__ o)
{
    __shared__ _Float16 Ks[256 * 20];
    __shared__ _Float16 Vs[16 * 264];

    const int bh   = blockIdx.x;
    const int qc   = blockIdx.y;
    const int b    = bh >> 3;
    const int h    = bh & 7;
    const int tid  = threadIdx.x;
    const int wave = tid >> 6;
    const int lane = tid & 63;
    const int quad = lane >> 4;
    const int m16  = lane & 15;
    const int q0   = qc * 128 + wave * 32;

    const f16x4 qf0 = *(const f16x4*)(q + (((size_t)bh * Sq) + q0 + m16) * DHq + quad * 4);
    const f16x4 qf1 = *(const f16x4*)(q + (((size_t)bh * Sq) + q0 + 16 + m16) * DHq + quad * 4);

    const _Float16* kg  = k  + (size_t)bh * Sq * DHq;
    const _Float16* vtg = vt + (size_t)bh * DHq * Sq;

    f32x4 oacc0 = (f32x4)0.f, oacc1 = (f32x4)0.f;
    float lacc0 = 0.f, lacc1 = 0.f;

    const int krow = tid;
    const int vrow = tid >> 4;
    const int vcol = (tid & 15) * 16;

    for (int kb = 0; kb < 4; ++kb) {
        f16x8 ka  = *(const f16x8*)(kg + ((size_t)kb * 256 + krow) * DHq);
        f16x8 kb8 = *(const f16x8*)(kg + ((size_t)kb * 256 + krow) * DHq + 8);
        f16x8 va  = *(const f16x8*)(vtg + (size_t)vrow * Sq + kb * 256 + vcol);
        f16x8 vb  = *(const f16x8*)(vtg + (size_t)vrow * Sq + kb * 256 + vcol + 8);
        __syncthreads();
        *(f16x8*)&Ks[krow * 20 + 0] = ka;
        *(f16x8*)&Ks[krow * 20 + 8] = kb8;
        *(f16x8*)&Vs[vrow * 264 + vcol + 0] = va;
        *(f16x8*)&Vs[vrow * 264 + vcol + 8] = vb;
        __syncthreads();

        #pragma unroll 4
        for (int kt = 0; kt < 16; ++kt) {
            const f16x4 kf = *(const f16x4*)&Ks[(kt * 16 + m16) * 20 + quad * 4];
            const f16x4 vf = *(const f16x4*)&Vs[m16 * 264 + kt * 16 + quad * 4];

            f32x4 st0 = __builtin_amdgcn_mfma_f32_16x16x16f16(kf, qf0, (f32x4)0.f, 0, 0, 0);
            f32x4 st1 = __builtin_amdgcn_mfma_f32_16x16x16f16(kf, qf1, (f32x4)0.f, 0, 0, 0);

            float p00 = __expf(st0[0]);
            float p01 = __expf(st0[1]);
            float p02 = __expf(st0[2]);
            float p03 = __expf(st0[3]);
            float p10 = __expf(st1[0]);
            float p11 = __expf(st1[1]);
            float p12 = __expf(st1[2]);
            float p13 = __expf(st1[3]);
            lacc0 += (p00 + p01) + (p02 + p03);
            lacc1 += (p10 + p11) + (p12 + p13);

            f16x4 pf0, pf1;
            pf0[0] = (_Float16)p00; pf0[1] = (_Float16)p01;
            pf0[2] = (_Float16)p02; pf0[3] = (_Float16)p03;
            pf1[0] = (_Float16)p10; pf1[1] = (_Float16)p11;
            pf1[2] = (_Float16)p12; pf1[3] = (_Float16)p13;

            oacc0 = __builtin_amdgcn_mfma_f32_16x16x16f16(pf0, vf, oacc0, 0, 0, 0);
            oacc1 = __builtin_amdgcn_mfma_f32_16x16x16f16(pf1, vf, oacc1, 0, 0, 0);
        }
    }

    lacc0 += __shfl_xor(lacc0, 16, 64);
    lacc0 += __shfl_xor(lacc0, 32, 64);
    lacc1 += __shfl_xor(lacc1, 16, 64);
    lacc1 += __shfl_xor(lacc1, 32, 64);

    #pragma unroll
    for (int r = 0; r < 4; ++r) {
        const float ls0 = __shfl(lacc0, quad * 4 + r, 64);
        const float ls1 = __shfl(lacc1, quad * 4 + r, 64);
        o[((size_t)b * Sq + q0 + quad * 4 + r) * Dq + h * DHq + m16]      = oacc0[r] / ls0;
        o[((size_t)b * Sq + q0 + 16 + quad * 4 + r) * Dq + h * DHq + m16] = oacc1[r] / ls1;
    }
}

// ---------------------------------------------------------------------------
extern "C" void kernel_launch(void* const* d_in, const int* in_sizes, int n_in,
                              void* d_out, int out_size, void* d_ws, size_t ws_size,
                              hipStream_t stream)
{
    const float* x_in  = (const float*)d_in[0];
    const float* Wq    = (const float*)d_in[1];
    const float* bq    = (const float*)d_in[2];
    const float* Wk    = (const float*)d_in[3];
    const float* bk    = (const float*)d_in[4];
    const float* Wv    = (const float*)d_in[5];
    const float* bv    = (const float*)d_in[6];
    const float* ln1_g = (const float*)d_in[7];
    const float* ln1_b = (const float*)d_in[8];
    const float* W1    = (const float*)d_in[9];
    const float* b1    = (const float*)d_in[10];
    const float* W2    = (const float*)d_in[11];
    const float* b2    = (const float*)d_in[12];
    const float* ln2_g = (const float*)d_in[13];
    const float* ln2_b = (const float*)d_in[14];
    const float* Wout  = (const float*)d_in[15];
    const float* bout  = (const float*)d_in[16];
    float* out = (float*)d_out;

    // Workspace (float units). h_bf spans [0, 2NX) and aliases q16/k16/vt16
    // (dead after attention). obuf at 8NX (ffn1_ln reads it while writing
    // h_bf). Total 9NX = 75.5 MB.
    float* ws = (float*)d_ws;
    _Float16* qf16 = (_Float16*)ws;                         // [0, 0.5NX)
    _Float16* kf16 = (_Float16*)(ws + NX / 2);              // [0.5, 1NX)
    _Float16* vt16 = (_Float16*)(ws + NX);                  // [1, 1.5NX)
    ushort*   h_bf = (ushort*)ws;                           // [0, 2NX)
    float*    xa   = ws + 7 * NX / 2;                       // [3.5, 4.5NX)
    float*    xb   = ws + 9 * NX / 2;                       // [4.5, 5.5NX)
    ushort*   xbf0 = (ushort*)(ws + 11 * NX / 2);           // [5.5, 6NX)
    ushort*   xbbf = (ushort*)(ws + 13 * NX / 2);           // [6.5, 7NX)
    ushort*   wbf  = (ushort*)(ws + 7 * NX);                // [7, ~7.26NX)
    float*    obuf = ws + 8 * NX;                           // [8, 9NX)

    prep_kernel<<<dim3(10304), dim3(256), 0, stream>>>(Wq, Wk, Wv, W1, W2, x_in, wbf, xbf0);

    const dim3 blk(256);
    const float* xcur = x_in;
    const ushort* xcur_bf = xbf0;

    for (int l = 0; l < Lq; ++l) {
        const ushort* wqt = wbf + (size_t)(0 * 3 + l) * 16384;
        const ushort* wkt = wbf + (size_t)(1 * 3 + l) * 16384;
        const ushort* wvt = wbf + (size_t)(2 * 3 + l) * 16384;
        const ushort* w1t = wbf + 147456 + (size_t)l * 65536;
        const ushort* w2t = wbf + 344064 + (size_t)l * 65536;

        gemm_qkv<<<dim3(256, 3), blk, 0, stream>>>(
            xcur_bf, wqt, wkt, wvt, bq + l * Dq, bk + l * Dq, bv + l * Dq,
            qf16, kf16, vt16);

        attn_mfma<<<dim3(Bq * Hq, 8), blk, 0, stream>>>(qf16, kf16, vt16, obuf);

        gemm_ffn1_ln<<<dim3(512), blk, 0, stream>>>(
            obuf, xcur, ln1_g + l * Dq, ln1_b + l * Dq, w1t, b1 + l * DFFq,
            xa, h_bf);

        gemm_ffn2_ln<<<dim3(256), blk, 0, stream>>>(
            h_bf, w2t, b2 + l * Dq, xa, ln2_g + l * Dq, ln2_b + l * Dq,
            xb, xbbf, Wout, bout, out, (l == Lq - 1) ? 1 : 0);

        xcur = xb;
        xcur_bf = xbbf;
    }
}

// Round 10
// 278.760 us; speedup vs baseline: 1.1501x; 1.0953x over previous
//
#include <hip/hip_runtime.h>
#include <math.h>

#define Bq 16
#define Sq 1024
#define Dq 128
#define Hq 8
#define DHq 16
#define DFFq 512
#define Lq 3
#define NCLS 6
#define NROWS (Bq * Sq)       // 16384
#define NX ((size_t)NROWS * Dq)   // 2,097,152 floats

typedef __attribute__((ext_vector_type(8))) short    bf16x8;
typedef __attribute__((ext_vector_type(4))) float    f32x4;
typedef __attribute__((ext_vector_type(4))) _Float16 f16x4;
typedef __attribute__((ext_vector_type(8))) _Float16 f16x8;

__device__ inline ushort f32_to_bf16(float f) {
    union { float f; unsigned u; } v; v.f = f;
    unsigned r = v.u + 0x7fffu + ((v.u >> 16) & 1u);
    return (ushort)(r >> 16);
}

// ---------------------------------------------------------------------------
// prep: cast+transpose weights to bf16 Wt[n][k]; cast x to bf16.
// Wq PRE-SCALED by 0.25 (ReLU commutes with positive scale).
// ---------------------------------------------------------------------------
__global__ __launch_bounds__(256) void prep_kernel(
    const float* __restrict__ Wqp, const float* __restrict__ Wkp,
    const float* __restrict__ Wvp, const float* __restrict__ W1p,
    const float* __restrict__ W2p, const float* __restrict__ xp,
    ushort* __restrict__ wbf, ushort* __restrict__ xbf)
{
    const int gid = blockIdx.x * 256 + threadIdx.x;
    if (gid < 147456) {                       // QKV transpose
        const int w   = gid / 49152;
        const int rem = gid - w * 49152;
        const int l   = rem >> 14;
        const int idx = rem & 16383;
        const int k   = idx >> 7;
        const int n   = idx & 127;
        const float* src = (w == 0) ? Wqp : (w == 1) ? Wkp : Wvp;
        const float scl = (w == 0) ? 0.25f : 1.0f;
        wbf[(size_t)(w * 3 + l) * 16384 + n * 128 + k] =
            f32_to_bf16(src[(size_t)l * 16384 + k * 128 + n] * scl);
    } else if (gid < 344064) {                // W1 [128][512]->[512][128]
        const int g   = gid - 147456;
        const int l   = g >> 16;
        const int idx = g & 65535;
        const int k   = idx >> 9;
        const int n   = idx & 511;
        wbf[147456 + (size_t)l * 65536 + n * 128 + k] =
            f32_to_bf16(W1p[(size_t)l * 65536 + k * 512 + n]);
    } else if (gid < 540672) {                // W2 [512][128]->[128][512]
        const int g   = gid - 344064;
        const int l   = g >> 16;
        const int idx = g & 65535;
        const int k   = idx >> 7;
        const int n   = idx & 127;
        wbf[344064 + (size_t)l * 65536 + n * 512 + k] =
            f32_to_bf16(W2p[(size_t)l * 65536 + k * 128 + n]);
    } else {                                  // x cast
        const int g = gid - 540672;
        xbf[g] = f32_to_bf16(xp[g]);
    }
}

// ---------------------------------------------------------------------------
// Fused QKV GEMM: grid (256, 3). y selects weight/bias/output layout.
// y=0: Q (pre-scaled) -> [b,h,s,dh] f16  y=1: K -> [b,h,s,dh] f16
// y=2: V -> vt [b,h,dh,s] f16
// ---------------------------------------------------------------------------
__global__ __launch_bounds__(256) void gemm_qkv(
    const ushort* __restrict__ A,
    const ushort* __restrict__ wq, const ushort* __restrict__ wk,
    const ushort* __restrict__ wv,
    const float* __restrict__ bqp, const float* __restrict__ bkp,
    const float* __restrict__ bvp,
    _Float16* __restrict__ qo, _Float16* __restrict__ ko,
    _Float16* __restrict__ vo)
{
    __shared__ ushort As[64 * 40];
    __shared__ ushort Bs[128 * 40];

    const int sel  = blockIdx.y;
    const ushort* Bt   = (sel == 0) ? wq : (sel == 1) ? wk : wv;
    const float*  bias = (sel == 0) ? bqp : (sel == 1) ? bkp : bvp;
    const float   bscl = (sel == 0) ? 0.25f : 1.0f;

    const int tid  = threadIdx.x;
    const int row0 = blockIdx.x * 64;
    const int wave = tid >> 6;
    const int lane = tid & 63;
    const int quad = lane >> 4;
    const int m16  = lane & 15;
    const int wm   = wave >> 1;
    const int wn   = wave & 1;

    const int sar = tid >> 2;
    const int sac = (tid & 3) * 8;

    f32x4 acc[2][4];
    #pragma unroll
    for (int i = 0; i < 2; ++i)
        #pragma unroll
        for (int j = 0; j < 4; ++j) acc[i][j] = (f32x4)0.f;

    for (int k0 = 0; k0 < 128; k0 += 32) {
        bf16x8 av = *(const bf16x8*)(A + (size_t)(row0 + sar) * 128 + k0 + sac);
        const int r1 = tid >> 2, r2 = r1 + 64;
        bf16x8 bv1 = *(const bf16x8*)(Bt + (size_t)r1 * 128 + k0 + sac);
        bf16x8 bv2 = *(const bf16x8*)(Bt + (size_t)r2 * 128 + k0 + sac);

        __syncthreads();
        *(bf16x8*)&As[sar * 40 + sac] = av;
        *(bf16x8*)&Bs[r1 * 40 + sac]  = bv1;
        *(bf16x8*)&Bs[r2 * 40 + sac]  = bv2;
        __syncthreads();

        bf16x8 af[2], bf[4];
        #pragma unroll
        for (int i = 0; i < 2; ++i)
            af[i] = *(const bf16x8*)&As[(32 * wm + 16 * i + m16) * 40 + quad * 8];
        #pragma unroll
        for (int j = 0; j < 4; ++j)
            bf[j] = *(const bf16x8*)&Bs[(64 * wn + 16 * j + m16) * 40 + quad * 8];
        #pragma unroll
        for (int i = 0; i < 2; ++i)
            #pragma unroll
            for (int j = 0; j < 4; ++j)
                acc[i][j] = __builtin_amdgcn_mfma_f32_16x16x32_bf16(af[i], bf[j], acc[i][j], 0, 0, 0);
    }

    #pragma unroll
    for (int i = 0; i < 2; ++i) {
        #pragma unroll
        for (int j = 0; j < 4; ++j) {
            const int col = 64 * wn + 16 * j + m16;
            const float bb = bias[col] * bscl;
            const int hh = col >> 4, dh = col & 15;
            #pragma unroll
            for (int r = 0; r < 4; ++r) {
                float val = fmaxf(acc[i][j][r] + bb, 0.f);
                const int gr = row0 + 32 * wm + 16 * i + quad * 4 + r;
                const int b = gr >> 10, s = gr & 1023;
                if (sel == 2) {
                    vo[(((size_t)b * Hq + hh) * DHq + dh) * Sq + s] = (_Float16)val;
                } else {
                    _Float16* outp = (sel == 0) ? qo : ko;
                    outp[(((size_t)b * Hq + hh) * Sq + s) * DHq + dh] = (_Float16)val;
                }
            }
        }
    }
}

// ---------------------------------------------------------------------------
// FULLY FUSED FFN BLOCK: LN1(o + resid) -> FFN1(relu) -> FFN2 -> +resid ->
// LN2 [-> final projection on last layer]. One 32-row block per 256-thr
// block, grid 512 (2 blocks/CU at 77.7 KB LDS).
//  - LN1: 8 rows/wave, each row exactly once (R9-proven). bf16 copy -> Af
//    (MFMA A operand), f32 copy -> vals (FFN2 residual — replaces xa buffer).
//  - FFN1: 4 col-chunks x 4 K-chunks; h (32x512 bf16) stays in LDS (Hs) —
//    the 32 MB/layer h_bf global round-trip is eliminated.
//  - FFN2: K=512 from resident Hs, staging only W2 tiles.
//  - LN2 in-block (full rows); last layer: 32x6 projection from LDS.
// ---------------------------------------------------------------------------
__global__ __launch_bounds__(256) void gemm_ffn_fused(
    const float* __restrict__ o, const float* __restrict__ resid,
    const float* __restrict__ g1, const float* __restrict__ beta1,
    const ushort* __restrict__ W1t, const float* __restrict__ bias1,
    const ushort* __restrict__ W2t, const float* __restrict__ bias2,
    const float* __restrict__ g2, const float* __restrict__ beta2,
    float* __restrict__ xb, ushort* __restrict__ xbbf,
    const float* __restrict__ Wout, const float* __restrict__ bout,
    float* __restrict__ out, int last)
{
    __shared__ __align__(16) char smem[77696];
    ushort* Af   = (ushort*)smem;                 // [0,17408): 32x136 bf16
    ushort* Hs   = (ushort*)(smem + 17408);       // [17408,50688): 32x520 bf16
    ushort* Bs   = (ushort*)(smem + 50688);       // [50688,60928): 128x40 staging
    float*  wo_s = (float*)(smem + 50688);        // overlays Bs in phase D
    float*  vals = (float*)(smem + 60928);        // [60928,77440): 32x129 f32
    float*  mus  = (float*)(smem + 77440);        // 32 f32
    float*  rsds = (float*)(smem + 77568);        // 32 f32

    const int tid  = threadIdx.x;
    const int row0 = blockIdx.x * 32;
    const int wave = tid >> 6;
    const int lane = tid & 63;
    const int quad = lane >> 4;
    const int m16  = lane & 15;
    const int wm   = wave >> 1;          // row half: 16*wm
    const int wn   = wave & 1;           // col half: 64*wn
    const int sac  = (tid & 3) * 8;
    const int r1   = tid >> 2, r2 = r1 + 64;

    // ---- Phase A: LN1, 8 rows/wave, each row once ----
    #pragma unroll 2
    for (int it = 0; it < 8; ++it) {
        const int rr = wave * 8 + it;
        const size_t base = (size_t)(row0 + rr) * Dq;
        float v0 = o[base + lane]      + resid[base + lane];
        float v1 = o[base + 64 + lane] + resid[base + 64 + lane];

        float s = v0 + v1;
        #pragma unroll
        for (int off = 32; off > 0; off >>= 1) s += __shfl_xor(s, off, 64);
        const float mu = s * (1.f / 128.f);
        const float d0 = v0 - mu, d1 = v1 - mu;
        float vs = d0 * d0 + d1 * d1;
        #pragma unroll
        for (int off = 32; off > 0; off >>= 1) vs += __shfl_xor(vs, off, 64);
        const float rstd = rsqrtf(vs * (1.f / 128.f) + 1e-8f);

        const float rv0 = g1[lane]      * d0 * rstd + beta1[lane];
        const float rv1 = g1[lane + 64] * d1 * rstd + beta1[lane + 64];
        Af[rr * 136 + lane]        = f32_to_bf16(rv0);
        Af[rr * 136 + 64 + lane]   = f32_to_bf16(rv1);
        vals[rr * 129 + lane]      = rv0;
        vals[rr * 129 + 64 + lane] = rv1;
    }

    // ---- Phase B: FFN1 (K=128), h -> Hs (resident) ----
    for (int cc = 0; cc < 4; ++cc) {
        f32x4 acc[4];
        #pragma unroll
        for (int j = 0; j < 4; ++j) acc[j] = (f32x4)0.f;

        for (int k0 = 0; k0 < 128; k0 += 32) {
            bf16x8 bv1 = *(const bf16x8*)(W1t + (size_t)(cc * 128 + r1) * 128 + k0 + sac);
            bf16x8 bv2 = *(const bf16x8*)(W1t + (size_t)(cc * 128 + r2) * 128 + k0 + sac);

            __syncthreads();     // 1st iter: also guards Phase-A LDS writes
            *(bf16x8*)&Bs[r1 * 40 + sac] = bv1;
            *(bf16x8*)&Bs[r2 * 40 + sac] = bv2;
            __syncthreads();

            const bf16x8 af = *(const bf16x8*)&Af[(16 * wm + m16) * 136 + k0 + quad * 8];
            bf16x8 bf[4];
            #pragma unroll
            for (int j = 0; j < 4; ++j)
                bf[j] = *(const bf16x8*)&Bs[(64 * wn + 16 * j + m16) * 40 + quad * 8];
            #pragma unroll
            for (int j = 0; j < 4; ++j)
                acc[j] = __builtin_amdgcn_mfma_f32_16x16x32_bf16(af, bf[j], acc[j], 0, 0, 0);
        }

        #pragma unroll
        for (int j = 0; j < 4; ++j) {
            const int col = cc * 128 + 64 * wn + 16 * j + m16;
            const float bb = bias1[col];
            #pragma unroll
            for (int r = 0; r < 4; ++r) {
                const int row = 16 * wm + quad * 4 + r;
                Hs[row * 520 + col] = f32_to_bf16(fmaxf(acc[j][r] + bb, 0.f));
            }
        }
    }

    // ---- Phase C: FFN2 (K=512) from resident Hs ----
    f32x4 acc2[4];
    #pragma unroll
    for (int j = 0; j < 4; ++j) acc2[j] = (f32x4)0.f;

    for (int k0 = 0; k0 < DFFq; k0 += 32) {
        bf16x8 bv1 = *(const bf16x8*)(W2t + (size_t)r1 * DFFq + k0 + sac);
        bf16x8 bv2 = *(const bf16x8*)(W2t + (size_t)r2 * DFFq + k0 + sac);

        __syncthreads();         // 1st iter: also guards Phase-B Hs writes
        *(bf16x8*)&Bs[r1 * 40 + sac] = bv1;
        *(bf16x8*)&Bs[r2 * 40 + sac] = bv2;
        __syncthreads();

        const bf16x8 af = *(const bf16x8*)&Hs[(16 * wm + m16) * 520 + k0 + quad * 8];
        bf16x8 bf[4];
        #pragma unroll
        for (int j = 0; j < 4; ++j)
            bf[j] = *(const bf16x8*)&Bs[(64 * wn + 16 * j + m16) * 40 + quad * 8];
        #pragma unroll
        for (int j = 0; j < 4; ++j)
            acc2[j] = __builtin_amdgcn_mfma_f32_16x16x32_bf16(af, bf[j], acc2[j], 0, 0, 0);
    }

    // ---- Phase D: +bias +LN1-residual (vals), LN2, write / project ----
    __syncthreads();   // all Bs reads done (wo_s may overlay); vals stable

    float vreg[4][4];
    #pragma unroll
    for (int j = 0; j < 4; ++j) {
        const int col = 64 * wn + 16 * j + m16;
        const float bb = bias2[col];
        #pragma unroll
        for (int r = 0; r < 4; ++r) {
            const int row = 16 * wm + quad * 4 + r;
            float v = acc2[j][r] + bb + vals[row * 129 + col];   // owner-exclusive slot
            vreg[j][r] = v;
            vals[row * 129 + col] = v;
        }
    }
    if (last) {
        #pragma unroll
        for (int i = 0; i < 3; ++i) wo_s[tid + i * 256] = Wout[tid + i * 256];
    }
    __syncthreads();

    if (tid < 32) {
        float s = 0.f, s2 = 0.f;
        #pragma unroll 8
        for (int c = 0; c < Dq; ++c) {
            float x = vals[tid * 129 + c];
            s += x; s2 = fmaf(x, x, s2);
        }
        const float mu  = s * (1.f / 128.f);
        const float var = s2 * (1.f / 128.f) - mu * mu;
        mus[tid]  = mu;
        rsds[tid] = rsqrtf(var + 1e-6f);
    }
    __syncthreads();

    if (!last) {
        #pragma unroll
        for (int j = 0; j < 4; ++j) {
            const int col = 64 * wn + 16 * j + m16;
            #pragma unroll
            for (int r = 0; r < 4; ++r) {
                const int row = 16 * wm + quad * 4 + r;
                const float rn = g2[col] * (vreg[j][r] - mus[row]) * rsds[row] + beta2[col];
                const size_t idx = (size_t)(row0 + row) * Dq + col;
                xb[idx]   = rn;
                xbbf[idx] = f32_to_bf16(rn);
            }
        }
    } else {
        #pragma unroll
        for (int j = 0; j < 4; ++j) {
            const int col = 64 * wn + 16 * j + m16;
            #pragma unroll
            for (int r = 0; r < 4; ++r) {
                const int row = 16 * wm + quad * 4 + r;
                vals[row * 129 + col] = g2[col] * (vreg[j][r] - mus[row]) * rsds[row] + beta2[col];
            }
        }
        __syncthreads();
        if (tid < 32 * NCLS) {
            const int row = tid / NCLS;
            const int c   = tid - row * NCLS;
            float a = bout[c];
            #pragma unroll 8
            for (int kk = 0; kk < Dq; ++kk)
                a = fmaf(vals[row * 129 + kk], wo_s[kk * NCLS + c], a);
            out[(size_t)(row0 + row) * NCLS + c] = a;
        }
    }
}

// ---------------------------------------------------------------------------
// f16 MFMA flash attention, LDS-staged (R6 structure, R7 pre-scaled Q).
// ---------------------------------------------------------------------------
__global__ __launch_bounds__(256) void attn_mfma(
    const _Float16* __restrict__ q, const _Float16* __restrict__ k,
    const _Float16* __restrict__ vt, float* __restrict__ o)
{
    __shared__ _Float16 Ks[256 * 20];
    __shared__ _Float16 Vs[16 * 264];

    const int bh   = blockIdx.x;
    const int qc   = blockIdx.y;
    const int b    = bh >> 3;
    const int h    = bh & 7;
    const int tid  = threadIdx.x;
    const int wave = tid >> 6;
    const int lane = tid & 63;
    const int quad = lane >> 4;
    const int m16  = lane & 15;
    const int q0   = qc * 128 + wave * 32;

    const f16x4 qf0 = *(const f16x4*)(q + (((size_t)bh * Sq) + q0 + m16) * DHq + quad * 4);
    const f16x4 qf1 = *(const f16x4*)(q + (((size_t)bh * Sq) + q0 + 16 + m16) * DHq + quad * 4);

    const _Float16* kg  = k  + (size_t)bh * Sq * DHq;
    const _Float16* vtg = vt + (size_t)bh * DHq * Sq;

    f32x4 oacc0 = (f32x4)0.f, oacc1 = (f32x4)0.f;
    float lacc0 = 0.f, lacc1 = 0.f;

    const int krow = tid;
    const int vrow = tid >> 4;
    const int vcol = (tid & 15) * 16;

    for (int kb = 0; kb < 4; ++kb) {
        f16x8 ka  = *(const f16x8*)(kg + ((size_t)kb * 256 + krow) * DHq);
        f16x8 kb8 = *(const f16x8*)(kg + ((size_t)kb * 256 + krow) * DHq + 8);
        f16x8 va  = *(const f16x8*)(vtg + (size_t)vrow * Sq + kb * 256 + vcol);
        f16x8 vb  = *(const f16x8*)(vtg + (size_t)vrow * Sq + kb * 256 + vcol + 8);
        __syncthreads();
        *(f16x8*)&Ks[krow * 20 + 0] = ka;
        *(f16x8*)&Ks[krow * 20 + 8] = kb8;
        *(f16x8*)&Vs[vrow * 264 + vcol + 0] = va;
        *(f16x8*)&Vs[vrow * 264 + vcol + 8] = vb;
        __syncthreads();

        #pragma unroll 4
        for (int kt = 0; kt < 16; ++kt) {
            const f16x4 kf = *(const f16x4*)&Ks[(kt * 16 + m16) * 20 + quad * 4];
            const f16x4 vf = *(const f16x4*)&Vs[m16 * 264 + kt * 16 + quad * 4];

            f32x4 st0 = __builtin_amdgcn_mfma_f32_16x16x16f16(kf, qf0, (f32x4)0.f, 0, 0, 0);
            f32x4 st1 = __builtin_amdgcn_mfma_f32_16x16x16f16(kf, qf1, (f32x4)0.f, 0, 0, 0);

            float p00 = __expf(st0[0]);
            float p01 = __expf(st0[1]);
            float p02 = __expf(st0[2]);
            float p03 = __expf(st0[3]);
            float p10 = __expf(st1[0]);
            float p11 = __expf(st1[1]);
            float p12 = __expf(st1[2]);
            float p13 = __expf(st1[3]);
            lacc0 += (p00 + p01) + (p02 + p03);
            lacc1 += (p10 + p11) + (p12 + p13);

            f16x4 pf0, pf1;
            pf0[0] = (_Float16)p00; pf0[1] = (_Float16)p01;
            pf0[2] = (_Float16)p02; pf0[3] = (_Float16)p03;
            pf1[0] = (_Float16)p10; pf1[1] = (_Float16)p11;
            pf1[2] = (_Float16)p12; pf1[3] = (_Float16)p13;

            oacc0 = __builtin_amdgcn_mfma_f32_16x16x16f16(pf0, vf, oacc0, 0, 0, 0);
            oacc1 = __builtin_amdgcn_mfma_f32_16x16x16f16(pf1, vf, oacc1, 0, 0, 0);
        }
    }

    lacc0 += __shfl_xor(lacc0, 16, 64);
    lacc0 += __shfl_xor(lacc0, 32, 64);
    lacc1 += __shfl_xor(lacc1, 16, 64);
    lacc1 += __shfl_xor(lacc1, 32, 64);

    #pragma unroll
    for (int r = 0; r < 4; ++r) {
        const float ls0 = __shfl(lacc0, quad * 4 + r, 64);
        const float ls1 = __shfl(lacc1, quad * 4 + r, 64);
        o[((size_t)b * Sq + q0 + quad * 4 + r) * Dq + h * DHq + m16]      = oacc0[r] / ls0;
        o[((size_t)b * Sq + q0 + 16 + quad * 4 + r) * Dq + h * DHq + m16] = oacc1[r] / ls1;
    }
}

// ---------------------------------------------------------------------------
extern "C" void kernel_launch(void* const* d_in, const int* in_sizes, int n_in,
                              void* d_out, int out_size, void* d_ws, size_t ws_size,
                              hipStream_t stream)
{
    const float* x_in  = (const float*)d_in[0];
    const float* Wq    = (const float*)d_in[1];
    const float* bq    = (const float*)d_in[2];
    const float* Wk    = (const float*)d_in[3];
    const float* bk    = (const float*)d_in[4];
    const float* Wv    = (const float*)d_in[5];
    const float* bv    = (const float*)d_in[6];
    const float* ln1_g = (const float*)d_in[7];
    const float* ln1_b = (const float*)d_in[8];
    const float* W1    = (const float*)d_in[9];
    const float* b1    = (const float*)d_in[10];
    const float* W2    = (const float*)d_in[11];
    const float* b2    = (const float*)d_in[12];
    const float* ln2_g = (const float*)d_in[13];
    const float* ln2_b = (const float*)d_in[14];
    const float* Wout  = (const float*)d_in[15];
    const float* bout  = (const float*)d_in[16];
    float* out = (float*)d_out;

    // Workspace (float units). q/k/vt f16 at front (dead after attn).
    // obuf at 8NX. h/xa buffers no longer exist (LDS-resident in fused FFN).
    float* ws = (float*)d_ws;
    _Float16* qf16 = (_Float16*)ws;                         // [0, 0.5NX)
    _Float16* kf16 = (_Float16*)(ws + NX / 2);              // [0.5, 1NX)
    _Float16* vt16 = (_Float16*)(ws + NX);                  // [1, 1.5NX)
    float*    xb   = ws + 9 * NX / 2;                       // [4.5, 5.5NX)
    ushort*   xbf0 = (ushort*)(ws + 11 * NX / 2);           // [5.5, 6NX)
    ushort*   xbbf = (ushort*)(ws + 13 * NX / 2);           // [6.5, 7NX)
    ushort*   wbf  = (ushort*)(ws + 7 * NX);                // [7, ~7.26NX)
    float*    obuf = ws + 8 * NX;                           // [8, 9NX)

    prep_kernel<<<dim3(10304), dim3(256), 0, stream>>>(Wq, Wk, Wv, W1, W2, x_in, wbf, xbf0);

    const dim3 blk(256);
    const float* xcur = x_in;
    const ushort* xcur_bf = xbf0;

    for (int l = 0; l < Lq; ++l) {
        const ushort* wqt = wbf + (size_t)(0 * 3 + l) * 16384;
        const ushort* wkt = wbf + (size_t)(1 * 3 + l) * 16384;
        const ushort* wvt = wbf + (size_t)(2 * 3 + l) * 16384;
        const ushort* w1t = wbf + 147456 + (size_t)l * 65536;
        const ushort* w2t = wbf + 344064 + (size_t)l * 65536;

        gemm_qkv<<<dim3(256, 3), blk, 0, stream>>>(
            xcur_bf, wqt, wkt, wvt, bq + l * Dq, bk + l * Dq, bv + l * Dq,
            qf16, kf16, vt16);

        attn_mfma<<<dim3(Bq * Hq, 8), blk, 0, stream>>>(qf16, kf16, vt16, obuf);

        gemm_ffn_fused<<<dim3(512), blk, 0, stream>>>(
            obuf, xcur, ln1_g + l * Dq, ln1_b + l * Dq,
            w1t, b1 + l * DFFq, w2t, b2 + l * Dq,
            ln2_g + l * Dq, ln2_b + l * Dq,
            xb, xbbf, Wout, bout, out, (l == Lq - 1) ? 1 : 0);

        xcur = xb;
        xcur_bf = xbbf;
    }
}